// Round 14
// baseline (255.287 us; speedup 1.0000x reference)
//
#include <hip/hip_runtime.h>
#include <math.h>

// Router: x[8192,4096] fp32; Wg,Wc[64,4096]; scores=|cls*silu(gate)|, softmax,
// top-8 of scores+bias, weights = 1 + scores*extra_scale (gathered).
// Out: weights [8192,8] fp32, then indices [8192,8] written as float values.
//
// v13 = v12 + quad-buffered LDS with BK=64 phases: barriers halve (16->8 per
// slice), MFMA run per barrier doubles (48/wave). Mechanism: v12's per-step
// {B-wait -> ds_read -> MFMA -> split/ds_write -> lgkm(0) -> barrier} serialized
// pipes that should overlap; floor is max(MFMA 20.5us, x-HBM 21us) ~= 25us.
// LDS 48.8KB -> 3 blocks/CU. In-phase issue order: 12 B loads (oldest), then
// next-phase x loads (youngest) -- in-order vmcnt (m135) means MFMA waits
// vmcnt(10)/vmcnt(4) and never drains the HBM stream.
// Math/bits identical to v5..v12 (3-way bf16 split, 6-product order, same
// per-acc ascending-k chain, S=8) -> P bit-identical -> absmax 0.

#define T_DIM 8192
#define D_DIM 4096
#define E_DIM 64
#define N2    128      // 64 gate cols + 64 cls cols
#define KTOP  8
#define MB_ROWS 64     // rows per workgroup (wave = all 64 rows x 32 cols)

// LDS per-tile fragment layout strides (ushorts): [rg][p][h2][le][j]
#define LDS_H2S 512
#define LDS_PS  1040   // 1024 + 16 pad -> parts shifted 8 banks
#define LDS_RGS (3 * LDS_PS)
#define LDS_TS  (2 * LDS_RGS)   // one k32 tile = 6240 ushorts
// 4 tiles total: 24960 ushorts = 48.75 KB

typedef __attribute__((ext_vector_type(8)))  short bfrag8;   // 8 bf16 (4 VGPRs)
typedef __attribute__((ext_vector_type(16))) float f32x16;   // 32x32 C/D frag
typedef __attribute__((ext_vector_type(4)))  float f4;       // clang vec (nt ok)

__device__ __forceinline__ unsigned short f2bf_rne(float f) {
    unsigned int u = __float_as_uint(f);
    unsigned int r = u + 0x7fffu + ((u >> 16) & 1u);        // round-nearest-even
    return (unsigned short)(r >> 16);
}
__device__ __forceinline__ float bf2f(unsigned short h) {
    return __uint_as_float(((unsigned int)h) << 16);
}
// v = bf2f(h) + bf2f(m) + bf2f(l) + eps, |eps| <= 2^-27 |v|
__device__ __forceinline__ void split3(float v, unsigned short& h,
                                       unsigned short& m, unsigned short& l) {
    h = f2bf_rne(v);
    const float r1 = v - bf2f(h);          // exact in fp32
    m = f2bf_rne(r1);
    const float r2 = r1 - bf2f(m);         // exact in fp32
    l = f2bf_rne(r2);
}

// ---------------- Kernel 0: W -> packed fragment-major bf16 hi/mid/lo ----------
// Wpk element index: ((((k32*4 + n)*3 + p)*2 + h2)*64 + lane)*8 + j
//   holds part-p of W[col = n*32 + (lane&31)][k32*32 + h2*16 + (lane>>5)*8 + j]
// => a wave's B fragment load is 64 lanes x 16B CONTIGUOUS (1 KB). Total 3 MB.
__global__ __launch_bounds__(256)
void router_prep(const float* __restrict__ Wg, const float* __restrict__ Wc,
                 unsigned short* __restrict__ Wpk)
{
    const int t   = blockIdx.x * 256 + threadIdx.x;  // 65536 threads
    const int col = t >> 9;                          // 0..127
    const int ch  = t & 511;                         // 8-float chunk within row
    const int k   = ch << 3;

    const float* src = (col < E_DIM) ? (Wg + (size_t)col * D_DIM)
                                     : (Wc + (size_t)(col - E_DIM) * D_DIM);
    const float4 w0 = ((const float4*)(src + k))[0];
    const float4 w1 = ((const float4*)(src + k))[1];
    const float v[8] = {w0.x, w0.y, w0.z, w0.w, w1.x, w1.y, w1.z, w1.w};

    unsigned short hv[8], mv[8], lv[8];
    #pragma unroll
    for (int j = 0; j < 8; ++j) split3(v[j], hv[j], mv[j], lv[j]);

    const int k32 = k >> 5, h2 = (k >> 4) & 1, lh = (k >> 3) & 1;
    const int n = col >> 5, lane = lh * 32 + (col & 31);
    const size_t base = ((((size_t)k32 * 4 + n) * 3 + 0) * 2 + h2) * 512 + (size_t)lane * 8;
    // p stride = 2*512 = 1024 elements
    *(ushort4*)(Wpk + base)          = make_ushort4(hv[0], hv[1], hv[2], hv[3]);
    *(ushort4*)(Wpk + base + 4)      = make_ushort4(hv[4], hv[5], hv[6], hv[7]);
    *(ushort4*)(Wpk + base + 1024)   = make_ushort4(mv[0], mv[1], mv[2], mv[3]);
    *(ushort4*)(Wpk + base + 1028)   = make_ushort4(mv[4], mv[5], mv[6], mv[7]);
    *(ushort4*)(Wpk + base + 2048)   = make_ushort4(lv[0], lv[1], lv[2], lv[3]);
    *(ushort4*)(Wpk + base + 2052)   = make_ushort4(lv[4], lv[5], lv[6], lv[7]);
}

// ---------------- Kernel 1: 3-way-split MFMA GEMM, partials P[ks][T][128] ------
// Block: 256 thr = 4 waves; wave wc owns cols wc*32..wc*32+31 and ALL 64 rows
// (two 32-row groups -> acc[2]). Quad-buffer: phase p reads tiles {2p,2p+1}
// (slots mod 4), writes prefetched tiles {2p+2,2p+3} into the other 2 slots.
__global__ __launch_bounds__(256, 3)
void router_gemm(const float* __restrict__ x,
                 const unsigned short* __restrict__ Wpk,
                 float* __restrict__ P,
                 int sliceK)
{
    __shared__ unsigned short sF[4 * LDS_TS];        // 48.75 KB

    const int tid  = threadIdx.x;
    const int lane = tid & 63;
    const int wc   = tid >> 6;           // wave = col-quarter (B n-tile)
    const int l31  = lane & 31;
    const int lh   = lane >> 5;
    const int mb   = blockIdx.x;
    const int ks   = blockIdx.y;
    const int k0   = ks * sliceK;
    const int NT   = sliceK >> 5;        // 32-k steps (16; even)
    const int NP   = NT >> 1;            // 64-k phases (8)
    const int brow0 = mb * MB_ROWS;

    // staging map: thread -> (srow, kq); covers rows srow and srow+32
    const int srow = tid >> 3;           // 0..31
    const int kq   = tid & 7;            // float4 chunk within 32-k step
    const int h2w  = kq >> 2;
    const int lew  = ((kq >> 1) & 1) * 32 + srow;
    const int jw   = (kq & 1) * 4;
    const int wbase = h2w * LDS_H2S + lew * 8 + jw;  // + slot*TS + rg*RGS + p*PS
    const float* gsrc0 = x + (size_t)(brow0 + srow) * D_DIM + k0 + kq * 4;
    const float* gsrc1 = gsrc0 + (size_t)32 * D_DIM;

    f32x16 acc[2];
    #pragma unroll
    for (int rg = 0; rg < 2; ++rg)
        #pragma unroll
        for (int r = 0; r < 16; ++r) acc[rg][r] = 0.f;

    // split one f4 into LDS tile slot_ at row-group rg_
    #define WRITE_HALF(v_, slot_, rg_)                                           \
        {                                                                        \
            ushort4 hv_, mv_, lv_;                                               \
            unsigned short h_, m_, l_;                                           \
            split3((v_).x, h_, m_, l_); hv_.x = h_; mv_.x = m_; lv_.x = l_;      \
            split3((v_).y, h_, m_, l_); hv_.y = h_; mv_.y = m_; lv_.y = l_;      \
            split3((v_).z, h_, m_, l_); hv_.z = h_; mv_.z = m_; lv_.z = l_;      \
            split3((v_).w, h_, m_, l_); hv_.w = h_; mv_.w = m_; lv_.w = l_;      \
            const int o_ = (slot_) * LDS_TS + (rg_) * LDS_RGS + wbase;           \
            *(ushort4*)&sF[o_]              = hv_;                               \
            *(ushort4*)&sF[o_ + LDS_PS]     = mv_;                               \
            *(ushort4*)&sF[o_ + 2 * LDS_PS] = lv_;                               \
        }

    // load k32-step t_'s 6 B fragments into named set SET (wave-contiguous, L2)
    #define LOAD_B(SET, t_)                                                      \
        {                                                                        \
            const size_t k32_ = (size_t)((k0 + (t_) * 32) >> 5);                 \
            const unsigned short* bb_ =                                          \
                Wpk + (((k32_ * 4 + wc) * 3) * 2 * 64 + (size_t)lane) * 8;       \
            SET##h0 = *(const bfrag8*)(bb_);                                     \
            SET##m0 = *(const bfrag8*)(bb_ + 1024);                              \
            SET##l0 = *(const bfrag8*)(bb_ + 2048);                              \
            SET##h1 = *(const bfrag8*)(bb_ + 512);                               \
            SET##m1 = *(const bfrag8*)(bb_ + 1536);                              \
            SET##l1 = *(const bfrag8*)(bb_ + 2560);                              \
        }

    // 24 MFMAs for the tile in slot_ with B set SET (per-acc order == v3..v12)
    #define MFMA_STEP(slot_, SET)                                                \
        {                                                                        \
            _Pragma("unroll")                                                    \
            for (int rg = 0; rg < 2; ++rg) {                                     \
                const int ab = (slot_) * LDS_TS + rg * LDS_RGS + lane * 8;       \
                const bfrag8 ah0 = *(const bfrag8*)&sF[ab];                      \
                const bfrag8 am0 = *(const bfrag8*)&sF[ab + LDS_PS];             \
                const bfrag8 al0 = *(const bfrag8*)&sF[ab + 2 * LDS_PS];         \
                const bfrag8 ah1 = *(const bfrag8*)&sF[ab + LDS_H2S];            \
                const bfrag8 am1 = *(const bfrag8*)&sF[ab + LDS_H2S + LDS_PS];   \
                const bfrag8 al1 = *(const bfrag8*)&sF[ab + LDS_H2S + 2 * LDS_PS]; \
                acc[rg] = __builtin_amdgcn_mfma_f32_32x32x16_bf16(ah0, SET##l0, acc[rg], 0, 0, 0); \
                acc[rg] = __builtin_amdgcn_mfma_f32_32x32x16_bf16(al0, SET##h0, acc[rg], 0, 0, 0); \
                acc[rg] = __builtin_amdgcn_mfma_f32_32x32x16_bf16(am0, SET##m0, acc[rg], 0, 0, 0); \
                acc[rg] = __builtin_amdgcn_mfma_f32_32x32x16_bf16(ah0, SET##m0, acc[rg], 0, 0, 0); \
                acc[rg] = __builtin_amdgcn_mfma_f32_32x32x16_bf16(am0, SET##h0, acc[rg], 0, 0, 0); \
                acc[rg] = __builtin_amdgcn_mfma_f32_32x32x16_bf16(ah0, SET##h0, acc[rg], 0, 0, 0); \
                acc[rg] = __builtin_amdgcn_mfma_f32_32x32x16_bf16(ah1, SET##l1, acc[rg], 0, 0, 0); \
                acc[rg] = __builtin_amdgcn_mfma_f32_32x32x16_bf16(al1, SET##h1, acc[rg], 0, 0, 0); \
                acc[rg] = __builtin_amdgcn_mfma_f32_32x32x16_bf16(am1, SET##m1, acc[rg], 0, 0, 0); \
                acc[rg] = __builtin_amdgcn_mfma_f32_32x32x16_bf16(ah1, SET##m1, acc[rg], 0, 0, 0); \
                acc[rg] = __builtin_amdgcn_mfma_f32_32x32x16_bf16(am1, SET##h1, acc[rg], 0, 0, 0); \
                acc[rg] = __builtin_amdgcn_mfma_f32_32x32x16_bf16(ah1, SET##h1, acc[rg], 0, 0, 0); \
            }                                                                    \
        }

    bfrag8 Xh0, Xm0, Xl0, Xh1, Xm1, Xl1;     // B set for even sub-step
    bfrag8 Yh0, Ym0, Yl0, Yh1, Ym1, Yl1;     // B set for odd sub-step

    // prologue: stage tiles 0,1 into slots 0,1; prefetch tiles 2,3 into xa
    {
        const f4 t0r0 = __builtin_nontemporal_load((const f4*)(gsrc0));
        const f4 t0r1 = __builtin_nontemporal_load((const f4*)(gsrc1));
        const f4 t1r0 = __builtin_nontemporal_load((const f4*)(gsrc0 + 32));
        const f4 t1r1 = __builtin_nontemporal_load((const f4*)(gsrc1 + 32));
        WRITE_HALF(t0r0, 0, 0);
        WRITE_HALF(t0r1, 0, 1);
        WRITE_HALF(t1r0, 1, 0);
        WRITE_HALF(t1r1, 1, 1);
    }
    f4 xa_a0 = {0,0,0,0}, xa_a1 = {0,0,0,0}, xa_b0 = {0,0,0,0}, xa_b1 = {0,0,0,0};
    f4 xb_a0, xb_a1, xb_b0, xb_b1;
    if (NT > 2) {
        xa_a0 = __builtin_nontemporal_load((const f4*)(gsrc0 + 64));
        xa_a1 = __builtin_nontemporal_load((const f4*)(gsrc1 + 64));
        xa_b0 = __builtin_nontemporal_load((const f4*)(gsrc0 + 96));
        xa_b1 = __builtin_nontemporal_load((const f4*)(gsrc1 + 96));
    }
    asm volatile("s_waitcnt lgkmcnt(0)" ::: "memory");
    __builtin_amdgcn_s_barrier();

    for (int p = 0; p < NP; ++p) {
        const int t0 = 2 * p;
        const int s0 = t0 & 3, s1 = (t0 + 1) & 3, s2 = (t0 + 2) & 3, s3 = (t0 + 3) & 3;

        // ---- all 12 B loads first (oldest), x prefetch last (youngest):
        //      MFMA(t0) waits vmcnt(10), MFMA(t0+1) waits vmcnt(4) -- the HBM
        //      x stream is never drained (in-order retirement, m135).
        LOAD_B(X, t0);
        LOAD_B(Y, t0 + 1);
        if (t0 + 4 < NT) {
            xb_a0 = __builtin_nontemporal_load((const f4*)(gsrc0 + (t0 + 4) * 32));
            xb_a1 = __builtin_nontemporal_load((const f4*)(gsrc1 + (t0 + 4) * 32));
            xb_b0 = __builtin_nontemporal_load((const f4*)(gsrc0 + (t0 + 5) * 32));
            xb_b1 = __builtin_nontemporal_load((const f4*)(gsrc1 + (t0 + 5) * 32));
        }

        // ---- 48 MFMAs under setprio (phase-split exists: 3 blocks/CU drift)
        __builtin_amdgcn_s_setprio(1);
        MFMA_STEP(s0, X);
        MFMA_STEP(s1, Y);
        __builtin_amdgcn_s_setprio(0);

        // ---- write prefetched tiles t0+2, t0+3 into the 2 slots not read
        if (t0 + 2 < NT) {
            WRITE_HALF(xa_a0, s2, 0);
            WRITE_HALF(xa_a1, s2, 1);
            WRITE_HALF(xa_b0, s3, 0);
            WRITE_HALF(xa_b1, s3, 1);
        }
        asm volatile("s_waitcnt lgkmcnt(0)" ::: "memory");
        __builtin_amdgcn_s_barrier();
        xa_a0 = xb_a0; xa_a1 = xb_a1; xa_b0 = xb_b0; xa_b1 = xb_b1;
    }
    #undef WRITE_HALF
    #undef LOAD_B
    #undef MFMA_STEP

    // store partial C tile: P[ks][row][col], non-temporal (read once by topk)
    // C/D (m74/m101): col = lane&31, row = (r&3) + 8*(r>>2) + 4*(lane>>5)
    #pragma unroll
    for (int rg = 0; rg < 2; ++rg) {
        float* Pb = P + ((size_t)ks * T_DIM + brow0 + rg * 32) * N2 + wc * 32 + l31;
        #pragma unroll
        for (int r = 0; r < 16; ++r) {
            const int wrow = (r & 3) + 8 * (r >> 2) + 4 * lh;
            __builtin_nontemporal_store(acc[rg][r], &Pb[(size_t)wrow * N2]);
        }
    }
}

// ---------------- Kernel 2: reduce slices + silu/abs/softmax + biased top-8 ----
// (unchanged from the passing kernel — exact index ordering proven)
__global__ __launch_bounds__(256)
void router_topk(const float* __restrict__ P,
                 const float* __restrict__ scale,
                 const float* __restrict__ bias,
                 float* __restrict__ out,
                 int ksplit)
{
    const int lane = threadIdx.x & 63;   // expert id
    const int wid  = threadIdx.x >> 6;
    const int row  = blockIdx.x * 4 + wid;

    float g = 0.f, c = 0.f;
    for (int ks = 0; ks < ksplit; ++ks) {
        const float* p = P + ((size_t)ks * T_DIM + row) * N2;
        g += p[lane];
        c += p[E_DIM + lane];
    }
    const float sg = g / (1.f + expf(-g));   // silu(gate)
    const float v  = fabsf(c * sg);          // score pre-softmax

    // fp32 softmax across the 64 lanes
    float m = v;
    #pragma unroll
    for (int off = 32; off >= 1; off >>= 1) m = fmaxf(m, __shfl_xor(m, off));
    const float e = expf(v - m);
    float Z = e;
    #pragma unroll
    for (int off = 32; off >= 1; off >>= 1) Z += __shfl_xor(Z, off);
    const float s = e / Z;

    const float sc  = scale[lane];
    float cur = s + bias[lane];              // selection key

    float myw = 0.f; int myi = 0;
    #pragma unroll
    for (int j = 0; j < KTOP; ++j) {
        // wave argmax, ties -> lowest index (matches jax.lax.top_k)
        float bv = cur; int bi = lane;
        #pragma unroll
        for (int off = 32; off >= 1; off >>= 1) {
            const float ov = __shfl_xor(bv, off);
            const int   oi = __shfl_xor(bi, off);
            if (ov > bv || (ov == bv && oi < bi)) { bv = ov; bi = oi; }
        }
        const float s_bi  = __shfl(s,  bi);
        const float sc_bi = __shfl(sc, bi);
        const float w = 1.f + s_bi * sc_bi;  // "original" gathered at bi
        if (lane == j)  { myw = w; myi = bi; }
        if (lane == bi) cur = -INFINITY;
    }

    if (lane < KTOP) {
        out[(size_t)row * KTOP + lane] = myw;
        out[(size_t)T_DIM * KTOP + (size_t)row * KTOP + lane] = (float)myi;
    }
}

extern "C" void kernel_launch(void* const* d_in, const int* in_sizes, int n_in,
                              void* d_out, int out_size, void* d_ws, size_t ws_size,
                              hipStream_t stream)
{
    const float* x  = (const float*)d_in[0];
    const float* Wg = (const float*)d_in[1];
    const float* Wc = (const float*)d_in[2];
    const float* sc = (const float*)d_in[3];
    const float* bs = (const float*)d_in[4];
    float* out = (float*)d_out;
    float* P   = (float*)d_ws;

    const size_t PER = (size_t)T_DIM * N2 * sizeof(float);           // 4 MB per slice
    const size_t WSP = (size_t)N2 * D_DIM * sizeof(unsigned short);  // 1 MB per W part

    // Need S*4MB (partials) + 3MB (packed W); degrade gracefully if ws is small.
    int S = 8;
    while (S > 1 && (size_t)S * PER + 3 * WSP > ws_size) S >>= 1;
    const int sliceK = D_DIM / S;

    unsigned short* Wpk = (unsigned short*)((char*)d_ws + (size_t)S * PER);

    router_prep<<<256, 256, 0, stream>>>(Wg, Wc, Wpk);
    router_gemm<<<dim3(T_DIM / MB_ROWS, S), 256, 0, stream>>>(x, Wpk, P, sliceK);
    router_topk<<<T_DIM / 4, 256, 0, stream>>>(P, sc, bs, out, S);
}

// Round 15
// 247.748 us; speedup vs baseline: 1.0304x; 1.0304x over previous
//
#include <hip/hip_runtime.h>
#include <math.h>

// Router: x[8192,4096] fp32; Wg,Wc[64,4096]; scores=|cls*silu(gate)|, softmax,
// top-8 of scores+bias, weights = 1 + scores*extra_scale (gathered).
// Out: weights [8192,8] fp32, then indices [8192,8] written as float values.
//
// v14 = v12 (best measured, 245.3us) with staging converted to ds_write_b128:
// thread -> (row, 8-float k-group) instead of (row, 4-float chunk). Same
// values to the same LDS addresses (only the writer assignment changes) ->
// LDS contents bit-identical -> P bit-identical -> absmax 0. Halves ds_write
// count (6x b64 -> 3x b128 per thread/tile) and cuts the 4.7e6 bank-conflict
// cycles (~10% of gemm). All else == v12: B loads first / x-prefetch youngest
// (in-order vmcnt, m135), depth-2 prefetch, setprio around MFMAs, 4 blocks/CU.

#define T_DIM 8192
#define D_DIM 4096
#define E_DIM 64
#define N2    128      // 64 gate cols + 64 cls cols
#define KTOP  8
#define MB_ROWS 64     // rows per workgroup (wave = all 64 rows x 32 cols)

// LDS fragment layout strides (ushorts): [bf][rg][p][h2][le][j]
#define LDS_H2S 512
#define LDS_PS  1040   // 1024 + 16 pad -> parts shifted 8 banks
#define LDS_RGS (3 * LDS_PS)
#define LDS_BFS (2 * LDS_RGS)

typedef __attribute__((ext_vector_type(8)))  short bfrag8;   // 8 bf16 (4 VGPRs)
typedef __attribute__((ext_vector_type(8)))  unsigned short us8;
typedef __attribute__((ext_vector_type(16))) float f32x16;   // 32x32 C/D frag
typedef __attribute__((ext_vector_type(4)))  float f4;       // clang vec (nt ok)

__device__ __forceinline__ unsigned short f2bf_rne(float f) {
    unsigned int u = __float_as_uint(f);
    unsigned int r = u + 0x7fffu + ((u >> 16) & 1u);        // round-nearest-even
    return (unsigned short)(r >> 16);
}
__device__ __forceinline__ float bf2f(unsigned short h) {
    return __uint_as_float(((unsigned int)h) << 16);
}
// v = bf2f(h) + bf2f(m) + bf2f(l) + eps, |eps| <= 2^-27 |v|
__device__ __forceinline__ void split3(float v, unsigned short& h,
                                       unsigned short& m, unsigned short& l) {
    h = f2bf_rne(v);
    const float r1 = v - bf2f(h);          // exact in fp32
    m = f2bf_rne(r1);
    const float r2 = r1 - bf2f(m);         // exact in fp32
    l = f2bf_rne(r2);
}

// ---------------- Kernel 0: W -> packed fragment-major bf16 hi/mid/lo ----------
// Wpk element index: ((((k32*4 + n)*3 + p)*2 + h2)*64 + lane)*8 + j
//   holds part-p of W[col = n*32 + (lane&31)][k32*32 + h2*16 + (lane>>5)*8 + j]
// => a wave's B fragment load is 64 lanes x 16B CONTIGUOUS (1 KB). Total 3 MB.
__global__ __launch_bounds__(256)
void router_prep(const float* __restrict__ Wg, const float* __restrict__ Wc,
                 unsigned short* __restrict__ Wpk)
{
    const int t   = blockIdx.x * 256 + threadIdx.x;  // 65536 threads
    const int col = t >> 9;                          // 0..127
    const int ch  = t & 511;                         // 8-float chunk within row
    const int k   = ch << 3;

    const float* src = (col < E_DIM) ? (Wg + (size_t)col * D_DIM)
                                     : (Wc + (size_t)(col - E_DIM) * D_DIM);
    const float4 w0 = ((const float4*)(src + k))[0];
    const float4 w1 = ((const float4*)(src + k))[1];
    const float v[8] = {w0.x, w0.y, w0.z, w0.w, w1.x, w1.y, w1.z, w1.w};

    unsigned short hv[8], mv[8], lv[8];
    #pragma unroll
    for (int j = 0; j < 8; ++j) split3(v[j], hv[j], mv[j], lv[j]);

    const int k32 = k >> 5, h2 = (k >> 4) & 1, lh = (k >> 3) & 1;
    const int n = col >> 5, lane = lh * 32 + (col & 31);
    const size_t base = ((((size_t)k32 * 4 + n) * 3 + 0) * 2 + h2) * 512 + (size_t)lane * 8;
    // p stride = 2*512 = 1024 elements
    *(ushort4*)(Wpk + base)          = make_ushort4(hv[0], hv[1], hv[2], hv[3]);
    *(ushort4*)(Wpk + base + 4)      = make_ushort4(hv[4], hv[5], hv[6], hv[7]);
    *(ushort4*)(Wpk + base + 1024)   = make_ushort4(mv[0], mv[1], mv[2], mv[3]);
    *(ushort4*)(Wpk + base + 1028)   = make_ushort4(mv[4], mv[5], mv[6], mv[7]);
    *(ushort4*)(Wpk + base + 2048)   = make_ushort4(lv[0], lv[1], lv[2], lv[3]);
    *(ushort4*)(Wpk + base + 2052)   = make_ushort4(lv[4], lv[5], lv[6], lv[7]);
}

// ---------------- Kernel 1: 3-way-split MFMA GEMM, partials P[ks][T][128] ------
// Block: 256 thr = 4 waves; wave wc owns cols wc*32..wc*32+31 and ALL 64 rows
// (two 32-row groups -> acc[2]). Staging thread (srow=tid>>2, seg=tid&3) loads
// 8 contiguous floats of row srow (seg = h2,lh k-group; 2x nt f4, 128B/row
// coalesced per wave), split3 once, writes 3x ds_write_b128 fragment layout.
__global__ __launch_bounds__(256, 4)
void router_gemm(const float* __restrict__ x,
                 const unsigned short* __restrict__ Wpk,
                 float* __restrict__ P,
                 int sliceK)
{
    __shared__ unsigned short sF[2 * LDS_BFS];       // ~25 KB

    const int tid  = threadIdx.x;
    const int lane = tid & 63;
    const int wc   = tid >> 6;           // wave = col-quarter (B n-tile)
    const int l31  = lane & 31;
    const int lh   = lane >> 5;
    const int mb   = blockIdx.x;
    const int ks   = blockIdx.y;
    const int k0   = ks * sliceK;
    const int NT   = sliceK >> 5;        // 32-k steps
    const int brow0 = mb * MB_ROWS;

    // staging map: thread -> (srow 0..63, seg 0..3 = (h2, lh)); 8 floats
    const int srow = tid >> 2;
    const int seg  = tid & 3;
    const int h2w  = seg >> 1;
    const int lhw  = seg & 1;
    const int wbase = (srow >> 5) * LDS_RGS + h2w * LDS_H2S
                    + (lhw * 32 + (srow & 31)) * 8;  // + bf*BFS + p*PS
    const float* gsrc = x + (size_t)(brow0 + srow) * D_DIM + k0 + h2w * 16 + lhw * 8;

    f32x16 acc[2];
    #pragma unroll
    for (int rg = 0; rg < 2; ++rg)
        #pragma unroll
        for (int r = 0; r < 16; ++r) acc[rg][r] = 0.f;

    // split 8 staged floats into LDS buffer bf_: 3 x ds_write_b128
    #define WRITE_ONE(va_, vb_, bf_)                                             \
        {                                                                        \
            us8 hv_, mv_, lv_;                                                   \
            unsigned short h_, m_, l_;                                           \
            split3((va_).x, h_, m_, l_); hv_[0] = h_; mv_[0] = m_; lv_[0] = l_;  \
            split3((va_).y, h_, m_, l_); hv_[1] = h_; mv_[1] = m_; lv_[1] = l_;  \
            split3((va_).z, h_, m_, l_); hv_[2] = h_; mv_[2] = m_; lv_[2] = l_;  \
            split3((va_).w, h_, m_, l_); hv_[3] = h_; mv_[3] = m_; lv_[3] = l_;  \
            split3((vb_).x, h_, m_, l_); hv_[4] = h_; mv_[4] = m_; lv_[4] = l_;  \
            split3((vb_).y, h_, m_, l_); hv_[5] = h_; mv_[5] = m_; lv_[5] = l_;  \
            split3((vb_).z, h_, m_, l_); hv_[6] = h_; mv_[6] = m_; lv_[6] = l_;  \
            split3((vb_).w, h_, m_, l_); hv_[7] = h_; mv_[7] = m_; lv_[7] = l_;  \
            const int o_ = (bf_) * LDS_BFS + wbase;                              \
            *(us8*)&sF[o_]              = hv_;                                   \
            *(us8*)&sF[o_ + LDS_PS]     = mv_;                                   \
            *(us8*)&sF[o_ + 2 * LDS_PS] = lv_;                                   \
        }

    // prologue: stage tile 0, start prefetch of tile 1
    {
        const f4 v0 = __builtin_nontemporal_load((const f4*)gsrc);
        const f4 v1 = __builtin_nontemporal_load((const f4*)(gsrc + 4));
        WRITE_ONE(v0, v1, 0);
    }
    f4 xa0 = {0,0,0,0}, xa1 = {0,0,0,0};   // data for tile t+1
    f4 xb0 = {0,0,0,0}, xb1 = {0,0,0,0};   // data for tile t+2
    if (NT > 1) {
        xa0 = __builtin_nontemporal_load((const f4*)(gsrc + 32));
        xa1 = __builtin_nontemporal_load((const f4*)(gsrc + 36));
    }
    asm volatile("s_waitcnt lgkmcnt(0)" ::: "memory");
    __builtin_amdgcn_s_barrier();

    for (int t = 0; t < NT; ++t) {
        const int bf = t & 1;
        const size_t k32 = (size_t)((k0 + t * 32) >> 5);

        // ---- B loads FIRST (L2-hot): MFMA's B-wait = vmcnt(2), never drains
        //      the HBM x-prefetch issued below (in-order retirement, m135).
        const unsigned short* bb =
            Wpk + (((k32 * 4 + wc) * 3) * 2 * 64 + (size_t)lane) * 8;
        const bfrag8 bh0 = *(const bfrag8*)(bb);
        const bfrag8 bm0 = *(const bfrag8*)(bb + 1024);
        const bfrag8 bl0 = *(const bfrag8*)(bb + 2048);
        const bfrag8 bh1 = *(const bfrag8*)(bb + 512);
        const bfrag8 bm1 = *(const bfrag8*)(bb + 1536);
        const bfrag8 bl1 = *(const bfrag8*)(bb + 2560);

        // ---- x prefetch LAST (youngest; depth-2 -> consumed next step)
        if (t + 2 < NT) {
            xb0 = __builtin_nontemporal_load((const f4*)(gsrc + (t + 2) * 32));
            xb1 = __builtin_nontemporal_load((const f4*)(gsrc + (t + 2) * 32 + 4));
        }

        // ---- A frags (linear conflict-free ds_read_b128) + MFMAs; per-acc
        //      order identical to v3..v13 (h2=0 six, then h2=1 six).
        __builtin_amdgcn_s_setprio(1);
        #pragma unroll
        for (int rg = 0; rg < 2; ++rg) {
            const int ab = bf * LDS_BFS + rg * LDS_RGS + lane * 8;
            const bfrag8 ah0 = *(const bfrag8*)&sF[ab];
            const bfrag8 am0 = *(const bfrag8*)&sF[ab + LDS_PS];
            const bfrag8 al0 = *(const bfrag8*)&sF[ab + 2 * LDS_PS];
            const bfrag8 ah1 = *(const bfrag8*)&sF[ab + LDS_H2S];
            const bfrag8 am1 = *(const bfrag8*)&sF[ab + LDS_H2S + LDS_PS];
            const bfrag8 al1 = *(const bfrag8*)&sF[ab + LDS_H2S + 2 * LDS_PS];
            // h2 = 0, smallest products first
            acc[rg] = __builtin_amdgcn_mfma_f32_32x32x16_bf16(ah0, bl0, acc[rg], 0, 0, 0);
            acc[rg] = __builtin_amdgcn_mfma_f32_32x32x16_bf16(al0, bh0, acc[rg], 0, 0, 0);
            acc[rg] = __builtin_amdgcn_mfma_f32_32x32x16_bf16(am0, bm0, acc[rg], 0, 0, 0);
            acc[rg] = __builtin_amdgcn_mfma_f32_32x32x16_bf16(ah0, bm0, acc[rg], 0, 0, 0);
            acc[rg] = __builtin_amdgcn_mfma_f32_32x32x16_bf16(am0, bh0, acc[rg], 0, 0, 0);
            acc[rg] = __builtin_amdgcn_mfma_f32_32x32x16_bf16(ah0, bh0, acc[rg], 0, 0, 0);
            // h2 = 1
            acc[rg] = __builtin_amdgcn_mfma_f32_32x32x16_bf16(ah1, bl1, acc[rg], 0, 0, 0);
            acc[rg] = __builtin_amdgcn_mfma_f32_32x32x16_bf16(al1, bh1, acc[rg], 0, 0, 0);
            acc[rg] = __builtin_amdgcn_mfma_f32_32x32x16_bf16(am1, bm1, acc[rg], 0, 0, 0);
            acc[rg] = __builtin_amdgcn_mfma_f32_32x32x16_bf16(ah1, bm1, acc[rg], 0, 0, 0);
            acc[rg] = __builtin_amdgcn_mfma_f32_32x32x16_bf16(am1, bh1, acc[rg], 0, 0, 0);
            acc[rg] = __builtin_amdgcn_mfma_f32_32x32x16_bf16(ah1, bh1, acc[rg], 0, 0, 0);
        }
        __builtin_amdgcn_s_setprio(0);

        // ---- write tile t+1 (xa issued a full step ago -> already retired)
        if (t + 1 < NT) WRITE_ONE(xa0, xa1, bf ^ 1);
        // barrier: LDS visibility only -- x prefetch stays in flight
        asm volatile("s_waitcnt lgkmcnt(0)" ::: "memory");
        __builtin_amdgcn_s_barrier();
        xa0 = xb0; xa1 = xb1;
    }
    #undef WRITE_ONE

    // store partial C tile: P[ks][row][col], non-temporal (read once by topk)
    // C/D (m74/m101): col = lane&31, row = (r&3) + 8*(r>>2) + 4*(lane>>5)
    #pragma unroll
    for (int rg = 0; rg < 2; ++rg) {
        float* Pb = P + ((size_t)ks * T_DIM + brow0 + rg * 32) * N2 + wc * 32 + l31;
        #pragma unroll
        for (int r = 0; r < 16; ++r) {
            const int wrow = (r & 3) + 8 * (r >> 2) + 4 * lh;
            __builtin_nontemporal_store(acc[rg][r], &Pb[(size_t)wrow * N2]);
        }
    }
}

// ---------------- Kernel 2: reduce slices + silu/abs/softmax + biased top-8 ----
// (unchanged from the passing kernel — exact index ordering proven)
__global__ __launch_bounds__(256)
void router_topk(const float* __restrict__ P,
                 const float* __restrict__ scale,
                 const float* __restrict__ bias,
                 float* __restrict__ out,
                 int ksplit)
{
    const int lane = threadIdx.x & 63;   // expert id
    const int wid  = threadIdx.x >> 6;
    const int row  = blockIdx.x * 4 + wid;

    float g = 0.f, c = 0.f;
    for (int ks = 0; ks < ksplit; ++ks) {
        const float* p = P + ((size_t)ks * T_DIM + row) * N2;
        g += p[lane];
        c += p[E_DIM + lane];
    }
    const float sg = g / (1.f + expf(-g));   // silu(gate)
    const float v  = fabsf(c * sg);          // score pre-softmax

    // fp32 softmax across the 64 lanes
    float m = v;
    #pragma unroll
    for (int off = 32; off >= 1; off >>= 1) m = fmaxf(m, __shfl_xor(m, off));
    const float e = expf(v - m);
    float Z = e;
    #pragma unroll
    for (int off = 32; off >= 1; off >>= 1) Z += __shfl_xor(Z, off);
    const float s = e / Z;

    const float sc  = scale[lane];
    float cur = s + bias[lane];              // selection key

    float myw = 0.f; int myi = 0;
    #pragma unroll
    for (int j = 0; j < KTOP; ++j) {
        // wave argmax, ties -> lowest index (matches jax.lax.top_k)
        float bv = cur; int bi = lane;
        #pragma unroll
        for (int off = 32; off >= 1; off >>= 1) {
            const float ov = __shfl_xor(bv, off);
            const int   oi = __shfl_xor(bi, off);
            if (ov > bv || (ov == bv && oi < bi)) { bv = ov; bi = oi; }
        }
        const float s_bi  = __shfl(s,  bi);
        const float sc_bi = __shfl(sc, bi);
        const float w = 1.f + s_bi * sc_bi;  // "original" gathered at bi
        if (lane == j)  { myw = w; myi = bi; }
        if (lane == bi) cur = -INFINITY;
    }

    if (lane < KTOP) {
        out[(size_t)row * KTOP + lane] = myw;
        out[(size_t)T_DIM * KTOP + (size_t)row * KTOP + lane] = (float)myi;
    }
}

extern "C" void kernel_launch(void* const* d_in, const int* in_sizes, int n_in,
                              void* d_out, int out_size, void* d_ws, size_t ws_size,
                              hipStream_t stream)
{
    const float* x  = (const float*)d_in[0];
    const float* Wg = (const float*)d_in[1];
    const float* Wc = (const float*)d_in[2];
    const float* sc = (const float*)d_in[3];
    const float* bs = (const float*)d_in[4];
    float* out = (float*)d_out;
    float* P   = (float*)d_ws;

    const size_t PER = (size_t)T_DIM * N2 * sizeof(float);           // 4 MB per slice
    const size_t WSP = (size_t)N2 * D_DIM * sizeof(unsigned short);  // 1 MB per W part

    // Need S*4MB (partials) + 3MB (packed W); degrade gracefully if ws is small.
    int S = 8;
    while (S > 1 && (size_t)S * PER + 3 * WSP > ws_size) S >>= 1;
    const int sliceK = D_DIM / S;

    unsigned short* Wpk = (unsigned short*)((char*)d_ws + (size_t)S * PER);

    router_prep<<<256, 256, 0, stream>>>(Wg, Wc, Wpk);
    router_gemm<<<dim3(T_DIM / MB_ROWS, S), 256, 0, stream>>>(x, Wpk, P, sliceK);
    router_topk<<<T_DIM / 4, 256, 0, stream>>>(P, sc, bs, out, S);
}